// Round 12
// baseline (337.666 us; speedup 1.0000x reference)
//
#include <hip/hip_runtime.h>

#define IN_F   4096
#define OUT_F  4096
#define N_TOK  8192
#define NW     (OUT_F * IN_F)          // 16777216 weight elements
#define SEL_TARGET 8388608u            // 0-based ascending index of kth (= NW - MAX_ITER)
#define CAND_CAP (1u << 20)            // 1M keys (expected ~205K)

// Magnitude window (f32 bit patterns, sign stripped): kth is the median of
// |w| ~ U[0, 2^-6)  =>  ~2^-7 = 0x3C000000 with sigma ~1.9e-6.  Window ~±50 sigma.
#define LO_BITS 0x3BFCA000u            // 0.0077133
#define HI_BITS 0x3C018000u            // 0.0079041

typedef unsigned int  u32;
typedef unsigned short u16;

typedef __bf16 bf16x8 __attribute__((ext_vector_type(8)));
typedef float  f32x4  __attribute__((ext_vector_type(4)));
typedef u32    u32x4  __attribute__((ext_vector_type(4)));   // nt-load capable
typedef u16    u16x8  __attribute__((ext_vector_type(8)));   // 16 B/lane stores

// scal layout: [2]=kth bits  [3]=win cand count  [4]=count below LO
//              [6]=overflow flag  [7]=fallback gate
// ---------- helpers ----------
__device__ inline u16 f2bf_rne(float f) {
    u32 u = __float_as_uint(f);
    u32 r = (u + 0x7fffu + ((u >> 16) & 1u)) >> 16;
    return (u16)r;
}

// ---------- K1: w-scan — provisional w16 write (16 B/lane), count<LO, window compact ----------
__global__ __launch_bounds__(256) void scanw_kernel(
    const uint4* __restrict__ wb, u16* __restrict__ w16,
    u32* __restrict__ cand, u32* __restrict__ cpos,
    u32* __restrict__ scal) {
    __shared__ u32 lbuf[4096];
    __shared__ u32 lpos[4096];
    __shared__ u32 lcnt, gbase, lblw;
    if (threadIdx.x == 0) { lcnt = 0; lblw = 0; }
    __syncthreads();

    const int base = blockIdx.x * 4096;   // uint4 units; 1024 blocks * 4096 = NW/4
    u32 cntb = 0;
    #pragma unroll 2
    for (int j = 0; j < 8; j++) {
        const int i0 = base + (threadIdx.x + j * 256) * 2;   // two consecutive uint4
        uint4 v0 = wb[i0];
        uint4 v1 = wb[i0 + 1];
        u32 r[8] = {v0.x, v0.y, v0.z, v0.w, v1.x, v1.y, v1.z, v1.w};
        u16x8 o;
        #pragma unroll
        for (int e = 0; e < 8; e++) {
            u32 kk = r[e] & 0x7fffffffu;
            cntb += (kk < LO_BITS) ? 1u : 0u;
            // provisional mask at LO: exact for all entries outside the window
            o[e] = (kk >= LO_BITS) ? f2bf_rne(__uint_as_float(r[e])) : (u16)0;
            if (kk >= LO_BITS && kk < HI_BITS) {
                u32 idx = atomicAdd(&lcnt, 1u);
                if (idx < 4096) { lbuf[idx] = kk; lpos[idx] = (u32)i0 * 4u + e; }
                else scal[6] = 1u;                 // per-block overflow -> fallback
            }
        }
        *(u16x8*)&w16[(size_t)i0 * 4] = o;
    }
    #pragma unroll
    for (int off = 32; off; off >>= 1) cntb += __shfl_down(cntb, off);
    if ((threadIdx.x & 63) == 0) atomicAdd(&lblw, cntb);
    __syncthreads();
    if (threadIdx.x == 0) {
        gbase = atomicAdd(&scal[3], min(lcnt, 4096u));
        atomicAdd(&scal[4], lblw);
    }
    __syncthreads();
    const u32 n = min(lcnt, 4096u), gb = gbase;
    for (u32 i = threadIdx.x; i < n; i += 256)
        if (gb + i < CAND_CAP) { cand[gb + i] = lbuf[i]; cpos[gb + i] = lpos[i]; }
}

// ---------- K2: block 0 = exact kth among window candidates; blocks 1..2048 = x->bf16 ----------
#define SCAN1024(part, t)                                            \
    do { _Pragma("unroll")                                           \
        for (int off_ = 1; off_ < 1024; off_ <<= 1) {                \
            u32 v_ = ((t) >= off_) ? part[(t) - off_] : 0u;          \
            __syncthreads();                                         \
            part[t] += v_;                                           \
            __syncthreads();                                         \
        } } while (0)

__global__ __launch_bounds__(1024) void mid_kernel(const u32* __restrict__ cand,
                                                   const uint4* __restrict__ wb,
                                                   const f32x4* __restrict__ xb,
                                                   u16* __restrict__ x16,
                                                   u32* __restrict__ scal) {
    if (blockIdx.x != 0) {
        const int nvec8 = (N_TOK * IN_F) / 8;     // pairs of f32x4
        const int stride = 2048 * 1024;
        for (int i = (blockIdx.x - 1) * 1024 + threadIdx.x; i < nvec8; i += stride) {
            f32x4 v0 = __builtin_nontemporal_load(&xb[2 * i]);
            f32x4 v1 = __builtin_nontemporal_load(&xb[2 * i + 1]);
            u16x8 o;
            o[0] = f2bf_rne(v0.x); o[1] = f2bf_rne(v0.y);
            o[2] = f2bf_rne(v0.z); o[3] = f2bf_rne(v0.w);
            o[4] = f2bf_rne(v1.x); o[5] = f2bf_rne(v1.y);
            o[6] = f2bf_rne(v1.z); o[7] = f2bf_rne(v1.w);
            *(u16x8*)&x16[(size_t)i * 8] = o;
        }
        return;
    }

    __shared__ u32 h[2048];
    __shared__ u32 part[1024];
    __shared__ u32 sh[2];
    const int t = threadIdx.x;
    const u32 n = scal[3], below = scal[4], ovf = scal[6];
    const bool valid = (n > 0) && (n <= CAND_CAP) && (ovf == 0) &&
                       (below <= SEL_TARGET) && (SEL_TARGET < below + n);

    if (valid) {
        u32 tgt = SEL_TARGET - below;
        const uint4* c4 = (const uint4*)cand;
        const u32 n4 = n >> 2;

        // L1: 624 bins over (key - LO) >> 9  (contention-free: <=512/bin)
        h[t] = 0; h[t + 1024] = 0;
        __syncthreads();
        for (u32 i = t; i < n4; i += 1024) {
            uint4 v = c4[i];
            atomicAdd(&h[(v.x - LO_BITS) >> 9], 1u);
            atomicAdd(&h[(v.y - LO_BITS) >> 9], 1u);
            atomicAdd(&h[(v.z - LO_BITS) >> 9], 1u);
            atomicAdd(&h[(v.w - LO_BITS) >> 9], 1u);
        }
        for (u32 i = (n4 << 2) + t; i < n; i += 1024)
            atomicAdd(&h[(cand[i] - LO_BITS) >> 9], 1u);
        __syncthreads();
        u32 c = h[t];
        part[t] = c;
        __syncthreads();
        SCAN1024(part, t);
        u32 cum = (t == 0) ? 0u : part[t - 1];
        if (tgt >= cum && tgt < cum + c) { sh[0] = (u32)t; sh[1] = tgt - cum; }
        __syncthreads();
        const u32 b1 = sh[0];
        tgt = sh[1];
        __syncthreads();

        // L2: exact — 512 bins over (key - LO) & 511, filtered to b1
        h[t] = 0; h[t + 1024] = 0;
        __syncthreads();
        for (u32 i = t; i < n4; i += 1024) {
            uint4 v = c4[i];
            u32 d0 = v.x - LO_BITS, d1 = v.y - LO_BITS,
                d2 = v.z - LO_BITS, d3 = v.w - LO_BITS;
            if ((d0 >> 9) == b1) atomicAdd(&h[d0 & 511u], 1u);
            if ((d1 >> 9) == b1) atomicAdd(&h[d1 & 511u], 1u);
            if ((d2 >> 9) == b1) atomicAdd(&h[d2 & 511u], 1u);
            if ((d3 >> 9) == b1) atomicAdd(&h[d3 & 511u], 1u);
        }
        for (u32 i = (n4 << 2) + t; i < n; i += 1024) {
            u32 d = cand[i] - LO_BITS;
            if ((d >> 9) == b1) atomicAdd(&h[d & 511u], 1u);
        }
        __syncthreads();
        c = (t < 512) ? h[t] : 0u;
        part[t] = c;
        __syncthreads();
        SCAN1024(part, t);
        cum = (t == 0) ? 0u : part[t - 1];
        if (tgt >= cum && tgt < cum + c)
            scal[2] = LO_BITS + (b1 << 9) + (u32)t;   // kth |w| bit pattern
        return;
    }

    // ---- embedded exact fallback (single block, 3-level radix over all keys).
    // Never taken for the expected distribution; correct (slow) otherwise.
    if (t == 0) scal[7] = 1u;    // finalize_w must do a full rewrite
    u32 tgt = SEL_TARGET;
    const int nvec = NW / 4;
    h[t] = 0; h[t + 1024] = 0;
    __syncthreads();
    for (int i = t; i < nvec; i += 1024) {
        uint4 v = wb[i];
        atomicAdd(&h[(v.x & 0x7fffffffu) >> 20], 1u);
        atomicAdd(&h[(v.y & 0x7fffffffu) >> 20], 1u);
        atomicAdd(&h[(v.z & 0x7fffffffu) >> 20], 1u);
        atomicAdd(&h[(v.w & 0x7fffffffu) >> 20], 1u);
    }
    __syncthreads();
    u32 a0 = h[2 * t], a1 = h[2 * t + 1];
    part[t] = a0 + a1;
    __syncthreads();
    SCAN1024(part, t);
    u32 cum = (t == 0) ? 0u : part[t - 1];
    if (tgt >= cum && tgt < cum + a0) { sh[0] = (u32)(2 * t);     sh[1] = tgt - cum; }
    cum += a0;
    if (tgt >= cum && tgt < cum + a1) { sh[0] = (u32)(2 * t + 1); sh[1] = tgt - cum; }
    __syncthreads();
    const u32 b1f = sh[0];
    tgt = sh[1];
    __syncthreads();

    h[t] = 0; h[t + 1024] = 0;
    __syncthreads();
    for (int i = t; i < nvec; i += 1024) {
        uint4 v = wb[i];
        u32 k[4] = {v.x & 0x7fffffffu, v.y & 0x7fffffffu,
                    v.z & 0x7fffffffu, v.w & 0x7fffffffu};
        #pragma unroll
        for (int e = 0; e < 4; e++)
            if ((k[e] >> 20) == b1f) atomicAdd(&h[(k[e] >> 9) & 2047u], 1u);
    }
    __syncthreads();
    a0 = h[2 * t]; a1 = h[2 * t + 1];
    part[t] = a0 + a1;
    __syncthreads();
    SCAN1024(part, t);
    cum = (t == 0) ? 0u : part[t - 1];
    if (tgt >= cum && tgt < cum + a0) { sh[0] = (u32)(2 * t);     sh[1] = tgt - cum; }
    cum += a0;
    if (tgt >= cum && tgt < cum + a1) { sh[0] = (u32)(2 * t + 1); sh[1] = tgt - cum; }
    __syncthreads();
    const u32 pfx22 = (b1f << 11) | sh[0];
    tgt = sh[1];
    __syncthreads();

    h[t] = 0; h[t + 1024] = 0;
    __syncthreads();
    for (int i = t; i < nvec; i += 1024) {
        uint4 v = wb[i];
        u32 k[4] = {v.x & 0x7fffffffu, v.y & 0x7fffffffu,
                    v.z & 0x7fffffffu, v.w & 0x7fffffffu};
        #pragma unroll
        for (int e = 0; e < 4; e++)
            if ((k[e] >> 9) == pfx22) atomicAdd(&h[k[e] & 511u], 1u);
    }
    __syncthreads();
    u32 c = (t < 512) ? h[t] : 0u;
    part[t] = c;
    __syncthreads();
    SCAN1024(part, t);
    cum = (t == 0) ? 0u : part[t - 1];
    if (tgt >= cum && tgt < cum + c)
        scal[2] = (pfx22 << 9) | (u32)t;
}

// ---------- K3: finalize w16 ----------
// normal path: zero the window candidates below kth (<=1M scattered u16 writes)
// fallback path (scal[7]==1): full masked rewrite from w
__global__ __launch_bounds__(256) void finalize_w_kernel(
    const u32* __restrict__ cand, const u32* __restrict__ cpos,
    const u32x4* __restrict__ wb, u16* __restrict__ w16,
    const u32* __restrict__ scal) {
    const u32 kth = scal[2];
    const u32 stride = gridDim.x * blockDim.x;
    if (scal[7] == 1u) {
        const u32 nvec = NW / 4;
        for (u32 i = blockIdx.x * blockDim.x + threadIdx.x; i < nvec; i += stride) {
            u32x4 v = __builtin_nontemporal_load(&wb[i]);
            ushort4 o;
            o.x = ((v.x & 0x7fffffffu) >= kth) ? f2bf_rne(__uint_as_float(v.x)) : (u16)0;
            o.y = ((v.y & 0x7fffffffu) >= kth) ? f2bf_rne(__uint_as_float(v.y)) : (u16)0;
            o.z = ((v.z & 0x7fffffffu) >= kth) ? f2bf_rne(__uint_as_float(v.z)) : (u16)0;
            o.w = ((v.w & 0x7fffffffu) >= kth) ? f2bf_rne(__uint_as_float(v.w)) : (u16)0;
            *(ushort4*)&w16[(size_t)i * 4] = o;
        }
    } else {
        const u32 n = min(scal[3], CAND_CAP);
        for (u32 i = blockIdx.x * blockDim.x + threadIdx.x; i < n; i += stride)
            if (cand[i] < kth) w16[cpos[i]] = (u16)0;
    }
}

// ---------- K4: 256x256 8-phase bf16 MFMA GEMM (m201 template, frozen schedule) ----------
#define BK 64
#define NT (IN_F / BK)   // 64 K-tiles

#define ASLOT(buf, ks) (((buf) * 2 + (ks)) * 8192)
#define BSLOT(buf, ks) (32768 + ((buf) * 2 + (ks)) * 8192)

#define VMCNT(n) asm volatile("s_waitcnt vmcnt(" #n ")" ::: "memory")
#define LGKM0    asm volatile("s_waitcnt lgkmcnt(0)" ::: "memory")
#define BARR()   __builtin_amdgcn_s_barrier()

__global__ __launch_bounds__(512, 2) void gemm8p(
    const u16* __restrict__ A,
    const u16* __restrict__ B,
    const float* __restrict__ bias,
    float* __restrict__ C) {
    __shared__ u16 lds[65536];   // 128 KiB

    const int tid  = threadIdx.x;
    const int lane = tid & 63;
    const int ln15 = lane & 15;
    const int l16  = lane >> 4;
    const int wv   = tid >> 6;
    const int wr   = wv >> 2;
    const int wc   = wv & 3;
    const int wrow = wr * 128;
    const int wcol = wc * 64;

    // XCD-bijective swizzle, column-major within XCD: the ~32 concurrently
    // resident blocks per XCD span 4 A-panels x 8 B-panels (24 MB lockstep
    // set, 4-way B-panel sharing) instead of 2 x 16 (36 MB, 2-way).
    const int bid = blockIdx.x;
    const int xcd = bid & 7;
    const int j   = bid >> 3;        // 0..63 within XCD
    const int by  = xcd * 4 + (j & 3);   // 0..31
    const int bx  = j >> 2;              // 0..15
    const int arow = by * 256;
    const int brow = bx * 256;

    f32x4 acc[8][4];
    #pragma unroll
    for (int m = 0; m < 8; m++)
        #pragma unroll
        for (int n = 0; n < 4; n++)
            acc[m][n] = {0.f, 0.f, 0.f, 0.f};

    #define STAGE(G, rowbase, kt, ks, slot) do {                                        \
        _Pragma("unroll")                                                               \
        for (int i_ = 0; i_ < 2; i_++) {                                                \
            int q_  = tid + i_ * 512;                                                   \
            int r_  = q_ >> 2;                                                          \
            int cs_ = (q_ & 3) ^ ((r_ >> 1) & 3);                                       \
            const u16* src_ = (G) + (size_t)((rowbase) + r_) * IN_F                     \
                              + (kt) * BK + (ks) * 32 + cs_ * 8;                        \
            __builtin_amdgcn_global_load_lds(                                           \
                (const __attribute__((address_space(1))) unsigned int*)src_,            \
                (__attribute__((address_space(3))) unsigned int*)&lds[(slot) + q_ * 8], \
                16, 0, 0);                                                              \
        } } while (0)

    #define READ_A(mh, ks, buf) do {                                                    \
        _Pragma("unroll")                                                               \
        for (int i_ = 0; i_ < 4; i_++) {                                                \
            int row_ = wrow + ((mh) * 4 + i_) * 16 + ln15;                              \
            int cc_  = l16 ^ ((row_ >> 1) & 3);                                         \
            aF[i_] = *(const bf16x8*)&lds[ASLOT(buf, ks) + row_ * 32 + cc_ * 8];        \
        } } while (0)

    #define READ_B(ks, buf) do {                                                       \
        _Pragma("unroll")                                                               \
        for (int i_ = 0; i_ < 4; i_++) {                                                \
            int row_ = wcol + i_ * 16 + ln15;                                           \
            int cc_  = l16 ^ ((row_ >> 1) & 3);                                         \
            bF[i_] = *(const bf16x8*)&lds[BSLOT(buf, ks) + row_ * 32 + cc_ * 8];        \
        } } while (0)

    #define MFMAQ(mh) do {                                                              \
        __builtin_amdgcn_s_setprio(1);                                                  \
        _Pragma("unroll")                                                               \
        for (int i_ = 0; i_ < 4; i_++)                                                  \
            _Pragma("unroll")                                                           \
            for (int n_ = 0; n_ < 4; n_++)                                              \
                acc[(mh) * 4 + i_][n_] = __builtin_amdgcn_mfma_f32_16x16x32_bf16(       \
                    aF[i_], bF[n_], acc[(mh) * 4 + i_][n_], 0, 0, 0);                   \
        __builtin_amdgcn_s_setprio(0);                                                  \
    } while (0)

    STAGE(B, brow, 0, 0, BSLOT(0, 0));
    STAGE(A, arow, 0, 0, ASLOT(0, 0));
    STAGE(B, brow, 0, 1, BSLOT(0, 1));
    STAGE(A, arow, 0, 1, ASLOT(0, 1));
    VMCNT(4);
    STAGE(B, brow, 1, 0, BSLOT(1, 0));
    STAGE(A, arow, 1, 0, ASLOT(1, 0));
    STAGE(B, brow, 1, 1, BSLOT(1, 1));
    VMCNT(6);
    BARR();

    bf16x8 aF[4], bF[4];

    #pragma unroll 1
    for (int it = 0; it < NT / 2; it++) {
        const int t0 = 2 * it;
        const int ka = t0 + 1;
        const int kb = (t0 + 2 < NT) ? t0 + 2 : NT - 1;
        const int kc = (t0 + 3 < NT) ? t0 + 3 : NT - 1;

        READ_A(0, 0, 0); READ_B(0, 0);
        STAGE(A, arow, ka, 1, ASLOT(1, 1));
        BARR(); LGKM0; MFMAQ(0); BARR();
        READ_A(1, 0, 0);
        STAGE(B, brow, kb, 0, BSLOT(0, 0));
        BARR(); LGKM0; MFMAQ(1); BARR();
        READ_A(0, 1, 0); READ_B(1, 0);
        STAGE(A, arow, kb, 0, ASLOT(0, 0));
        BARR(); LGKM0; MFMAQ(0); BARR();
        READ_A(1, 1, 0);
        STAGE(B, brow, kb, 1, BSLOT(0, 1));
        VMCNT(6);
        BARR(); LGKM0; MFMAQ(1); BARR();

        READ_A(0, 0, 1); READ_B(0, 1);
        STAGE(A, arow, kb, 1, ASLOT(0, 1));
        BARR(); LGKM0; MFMAQ(0); BARR();
        READ_A(1, 0, 1);
        STAGE(B, brow, kc, 0, BSLOT(1, 0));
        BARR(); LGKM0; MFMAQ(1); BARR();
        READ_A(0, 1, 1); READ_B(1, 1);
        STAGE(A, arow, kc, 0, ASLOT(1, 0));
        BARR(); LGKM0; MFMAQ(0); BARR();
        READ_A(1, 1, 1);
        STAGE(B, brow, kc, 1, BSLOT(1, 1));
        VMCNT(6);
        BARR(); LGKM0; MFMAQ(1); BARR();
    }
    VMCNT(0);

    // epilogue: nt stores — C is never re-read; keep L2/L3 for A/B panels
    const int cr = l16 * 4;
    #pragma unroll
    for (int n = 0; n < 4; n++) {
        int col = brow + wcol + n * 16 + ln15;
        float bv = bias[col];
        #pragma unroll
        for (int m = 0; m < 8; m++) {
            int r0 = arow + wrow + m * 16 + cr;
            #pragma unroll
            for (int j2 = 0; j2 < 4; j2++) {
                float vv = acc[m][n][j2] + bv;
                __builtin_nontemporal_store(vv, &C[(size_t)(r0 + j2) * OUT_F + col]);
            }
        }
    }
}

// ---------- launch ----------
extern "C" void kernel_launch(void* const* d_in, const int* in_sizes, int n_in,
                              void* d_out, int out_size, void* d_ws, size_t ws_size,
                              hipStream_t stream) {
    const float* x    = (const float*)d_in[0];
    const float* w    = (const float*)d_in[1];
    const float* bias = (const float*)d_in[2];
    float* out = (float*)d_out;

    char* ws = (char*)d_ws;
    u32* scal  = (u32*)(ws + 0);                             // 16 u32
    u16* w16   = (u16*)(ws + 65536);                         // 33.5 MB
    u16* x16   = (u16*)(ws + 65536 + (size_t)NW * 2);        // 67 MB
    // cand/cpos live in d_out (134 MB): read only by mid/finalize,
    // fully overwritten by gemm8p afterwards.  8 MB total.
    u32* cand  = (u32*)out;                                  // 4 MB
    u32* cpos  = cand + CAND_CAP;                            // 4 MB

    hipMemsetAsync(scal, 0, 64, stream);

    scanw_kernel<<<1024, 256, 0, stream>>>((const uint4*)w, w16, cand, cpos, scal);
    mid_kernel<<<2049, 1024, 0, stream>>>(cand, (const uint4*)w, (const f32x4*)x,
                                          x16, scal);
    finalize_w_kernel<<<2048, 256, 0, stream>>>(cand, cpos, (const u32x4*)w,
                                                w16, scal);

    gemm8p<<<512, 512, 0, stream>>>(x16, w16, bias, out);
}

// Round 13
// 333.452 us; speedup vs baseline: 1.0126x; 1.0126x over previous
//
#include <hip/hip_runtime.h>

#define IN_F   4096
#define OUT_F  4096
#define N_TOK  8192
#define NW     (OUT_F * IN_F)          // 16777216 weight elements
#define SEL_TARGET 8388608u            // 0-based ascending index of kth (= NW - MAX_ITER)
#define CAND_CAP (1u << 20)            // 1M keys (expected ~205K)

// Magnitude window (f32 bit patterns, sign stripped): kth is the median of
// |w| ~ U[0, 2^-6)  =>  ~2^-7 = 0x3C000000 with sigma ~1.9e-6.  Window ~±50 sigma.
#define LO_BITS 0x3BFCA000u            // 0.0077133
#define HI_BITS 0x3C018000u            // 0.0079041

typedef unsigned int  u32;
typedef unsigned short u16;

typedef __bf16 bf16x8 __attribute__((ext_vector_type(8)));
typedef float  f32x4  __attribute__((ext_vector_type(4)));
typedef u32    u32x4  __attribute__((ext_vector_type(4)));   // nt-load capable

// scal layout: [2]=kth bits  [3]=win cand count  [4]=count below LO
//              [6]=overflow flag  [7]=fallback gate
// ---------- helpers ----------
__device__ inline u16 f2bf_rne(float f) {
    u32 u = __float_as_uint(f);
    u32 r = (u + 0x7fffu + ((u >> 16) & 1u)) >> 16;
    return (u16)r;
}

// ---------- K1: w-scan — provisional w16 write, count<LO, window compact ----------
__global__ __launch_bounds__(256) void scanw_kernel(
    const uint4* __restrict__ wb, u16* __restrict__ w16,
    u32* __restrict__ cand, u32* __restrict__ cpos,
    u32* __restrict__ scal) {
    __shared__ u32 lbuf[4096];
    __shared__ u32 lpos[4096];
    __shared__ u32 lcnt, gbase, lblw;
    if (threadIdx.x == 0) { lcnt = 0; lblw = 0; }
    __syncthreads();

    const int base = blockIdx.x * 4096;   // uint4 units; 1024 blocks * 4096 = NW/4
    u32 cntb = 0;
    #pragma unroll 4
    for (int j = 0; j < 16; j++) {
        const int vi = base + threadIdx.x + j * 256;
        uint4 v = wb[vi];
        u32 r[4] = {v.x, v.y, v.z, v.w};
        ushort4 o;
        u16* op = (u16*)&o;
        #pragma unroll
        for (int e = 0; e < 4; e++) {
            u32 kk = r[e] & 0x7fffffffu;
            cntb += (kk < LO_BITS) ? 1u : 0u;
            // provisional mask at LO: exact for all entries outside the window
            op[e] = (kk >= LO_BITS) ? f2bf_rne(__uint_as_float(r[e])) : (u16)0;
            if (kk >= LO_BITS && kk < HI_BITS) {
                u32 idx = atomicAdd(&lcnt, 1u);
                if (idx < 4096) { lbuf[idx] = kk; lpos[idx] = (u32)vi * 4u + e; }
                else scal[6] = 1u;                 // per-block overflow -> fallback
            }
        }
        *(ushort4*)&w16[(size_t)vi * 4] = o;
    }
    #pragma unroll
    for (int off = 32; off; off >>= 1) cntb += __shfl_down(cntb, off);
    if ((threadIdx.x & 63) == 0) atomicAdd(&lblw, cntb);
    __syncthreads();
    if (threadIdx.x == 0) {
        gbase = atomicAdd(&scal[3], min(lcnt, 4096u));
        atomicAdd(&scal[4], lblw);
    }
    __syncthreads();
    const u32 n = min(lcnt, 4096u), gb = gbase;
    for (u32 i = threadIdx.x; i < n; i += 256)
        if (gb + i < CAND_CAP) { cand[gb + i] = lbuf[i]; cpos[gb + i] = lpos[i]; }
}

// ---------- K2: block 0 = exact kth among window candidates; blocks 1..2048 = x->bf16 ----------
#define SCAN1024(part, t)                                            \
    do { _Pragma("unroll")                                           \
        for (int off_ = 1; off_ < 1024; off_ <<= 1) {                \
            u32 v_ = ((t) >= off_) ? part[(t) - off_] : 0u;          \
            __syncthreads();                                         \
            part[t] += v_;                                           \
            __syncthreads();                                         \
        } } while (0)

__global__ __launch_bounds__(1024) void mid_kernel(const u32* __restrict__ cand,
                                                   const uint4* __restrict__ wb,
                                                   const f32x4* __restrict__ xb,
                                                   u16* __restrict__ x16,
                                                   u32* __restrict__ scal) {
    if (blockIdx.x != 0) {
        const int stride = 2048 * 1024;
        for (int i = (blockIdx.x - 1) * 1024 + threadIdx.x;
             i < (N_TOK * IN_F) / 4; i += stride) {
            f32x4 v = __builtin_nontemporal_load(&xb[i]);   // read-once stream
            ushort4 o;
            o.x = f2bf_rne(v.x);
            o.y = f2bf_rne(v.y);
            o.z = f2bf_rne(v.z);
            o.w = f2bf_rne(v.w);
            *(ushort4*)&x16[(size_t)i * 4] = o;
        }
        return;
    }

    __shared__ u32 h[2048];
    __shared__ u32 part[1024];
    __shared__ u32 sh[2];
    const int t = threadIdx.x;
    const u32 n = scal[3], below = scal[4], ovf = scal[6];
    const bool valid = (n > 0) && (n <= CAND_CAP) && (ovf == 0) &&
                       (below <= SEL_TARGET) && (SEL_TARGET < below + n);

    if (valid) {
        u32 tgt = SEL_TARGET - below;
        const uint4* c4 = (const uint4*)cand;
        const u32 n4 = n >> 2;

        // L1: 624 bins over (key - LO) >> 9  (contention-free: <=512/bin)
        h[t] = 0; h[t + 1024] = 0;
        __syncthreads();
        for (u32 i = t; i < n4; i += 1024) {
            uint4 v = c4[i];
            atomicAdd(&h[(v.x - LO_BITS) >> 9], 1u);
            atomicAdd(&h[(v.y - LO_BITS) >> 9], 1u);
            atomicAdd(&h[(v.z - LO_BITS) >> 9], 1u);
            atomicAdd(&h[(v.w - LO_BITS) >> 9], 1u);
        }
        for (u32 i = (n4 << 2) + t; i < n; i += 1024)
            atomicAdd(&h[(cand[i] - LO_BITS) >> 9], 1u);
        __syncthreads();
        u32 c = h[t];
        part[t] = c;
        __syncthreads();
        SCAN1024(part, t);
        u32 cum = (t == 0) ? 0u : part[t - 1];
        if (tgt >= cum && tgt < cum + c) { sh[0] = (u32)t; sh[1] = tgt - cum; }
        __syncthreads();
        const u32 b1 = sh[0];
        tgt = sh[1];
        __syncthreads();

        // L2: exact — 512 bins over (key - LO) & 511, filtered to b1
        h[t] = 0; h[t + 1024] = 0;
        __syncthreads();
        for (u32 i = t; i < n4; i += 1024) {
            uint4 v = c4[i];
            u32 d0 = v.x - LO_BITS, d1 = v.y - LO_BITS,
                d2 = v.z - LO_BITS, d3 = v.w - LO_BITS;
            if ((d0 >> 9) == b1) atomicAdd(&h[d0 & 511u], 1u);
            if ((d1 >> 9) == b1) atomicAdd(&h[d1 & 511u], 1u);
            if ((d2 >> 9) == b1) atomicAdd(&h[d2 & 511u], 1u);
            if ((d3 >> 9) == b1) atomicAdd(&h[d3 & 511u], 1u);
        }
        for (u32 i = (n4 << 2) + t; i < n; i += 1024) {
            u32 d = cand[i] - LO_BITS;
            if ((d >> 9) == b1) atomicAdd(&h[d & 511u], 1u);
        }
        __syncthreads();
        c = (t < 512) ? h[t] : 0u;
        part[t] = c;
        __syncthreads();
        SCAN1024(part, t);
        cum = (t == 0) ? 0u : part[t - 1];
        if (tgt >= cum && tgt < cum + c)
            scal[2] = LO_BITS + (b1 << 9) + (u32)t;   // kth |w| bit pattern
        return;
    }

    // ---- embedded exact fallback (single block, 3-level radix over all keys).
    // Never taken for the expected distribution; correct (slow) otherwise.
    if (t == 0) scal[7] = 1u;    // finalize_w must do a full rewrite
    u32 tgt = SEL_TARGET;
    const int nvec = NW / 4;
    h[t] = 0; h[t + 1024] = 0;
    __syncthreads();
    for (int i = t; i < nvec; i += 1024) {
        uint4 v = wb[i];
        atomicAdd(&h[(v.x & 0x7fffffffu) >> 20], 1u);
        atomicAdd(&h[(v.y & 0x7fffffffu) >> 20], 1u);
        atomicAdd(&h[(v.z & 0x7fffffffu) >> 20], 1u);
        atomicAdd(&h[(v.w & 0x7fffffffu) >> 20], 1u);
    }
    __syncthreads();
    u32 a0 = h[2 * t], a1 = h[2 * t + 1];
    part[t] = a0 + a1;
    __syncthreads();
    SCAN1024(part, t);
    u32 cum = (t == 0) ? 0u : part[t - 1];
    if (tgt >= cum && tgt < cum + a0) { sh[0] = (u32)(2 * t);     sh[1] = tgt - cum; }
    cum += a0;
    if (tgt >= cum && tgt < cum + a1) { sh[0] = (u32)(2 * t + 1); sh[1] = tgt - cum; }
    __syncthreads();
    const u32 b1f = sh[0];
    tgt = sh[1];
    __syncthreads();

    h[t] = 0; h[t + 1024] = 0;
    __syncthreads();
    for (int i = t; i < nvec; i += 1024) {
        uint4 v = wb[i];
        u32 k[4] = {v.x & 0x7fffffffu, v.y & 0x7fffffffu,
                    v.z & 0x7fffffffu, v.w & 0x7fffffffu};
        #pragma unroll
        for (int e = 0; e < 4; e++)
            if ((k[e] >> 20) == b1f) atomicAdd(&h[(k[e] >> 9) & 2047u], 1u);
    }
    __syncthreads();
    a0 = h[2 * t]; a1 = h[2 * t + 1];
    part[t] = a0 + a1;
    __syncthreads();
    SCAN1024(part, t);
    cum = (t == 0) ? 0u : part[t - 1];
    if (tgt >= cum && tgt < cum + a0) { sh[0] = (u32)(2 * t);     sh[1] = tgt - cum; }
    cum += a0;
    if (tgt >= cum && tgt < cum + a1) { sh[0] = (u32)(2 * t + 1); sh[1] = tgt - cum; }
    __syncthreads();
    const u32 pfx22 = (b1f << 11) | sh[0];
    tgt = sh[1];
    __syncthreads();

    h[t] = 0; h[t + 1024] = 0;
    __syncthreads();
    for (int i = t; i < nvec; i += 1024) {
        uint4 v = wb[i];
        u32 k[4] = {v.x & 0x7fffffffu, v.y & 0x7fffffffu,
                    v.z & 0x7fffffffu, v.w & 0x7fffffffu};
        #pragma unroll
        for (int e = 0; e < 4; e++)
            if ((k[e] >> 9) == pfx22) atomicAdd(&h[k[e] & 511u], 1u);
    }
    __syncthreads();
    u32 c = (t < 512) ? h[t] : 0u;
    part[t] = c;
    __syncthreads();
    SCAN1024(part, t);
    cum = (t == 0) ? 0u : part[t - 1];
    if (tgt >= cum && tgt < cum + c)
        scal[2] = (pfx22 << 9) | (u32)t;
}

// ---------- K3: finalize w16 ----------
__global__ __launch_bounds__(256) void finalize_w_kernel(
    const u32* __restrict__ cand, const u32* __restrict__ cpos,
    const u32x4* __restrict__ wb, u16* __restrict__ w16,
    const u32* __restrict__ scal) {
    const u32 kth = scal[2];
    const u32 stride = gridDim.x * blockDim.x;
    if (scal[7] == 1u) {
        const u32 nvec = NW / 4;
        for (u32 i = blockIdx.x * blockDim.x + threadIdx.x; i < nvec; i += stride) {
            u32x4 v = __builtin_nontemporal_load(&wb[i]);
            ushort4 o;
            o.x = ((v.x & 0x7fffffffu) >= kth) ? f2bf_rne(__uint_as_float(v.x)) : (u16)0;
            o.y = ((v.y & 0x7fffffffu) >= kth) ? f2bf_rne(__uint_as_float(v.y)) : (u16)0;
            o.z = ((v.z & 0x7fffffffu) >= kth) ? f2bf_rne(__uint_as_float(v.z)) : (u16)0;
            o.w = ((v.w & 0x7fffffffu) >= kth) ? f2bf_rne(__uint_as_float(v.w)) : (u16)0;
            *(ushort4*)&w16[(size_t)i * 4] = o;
        }
    } else {
        const u32 n = min(scal[3], CAND_CAP);
        for (u32 i = blockIdx.x * blockDim.x + threadIdx.x; i < n; i += stride)
            if (cand[i] < kth) w16[cpos[i]] = (u16)0;
    }
}

// ---------- K4: 256x256 8-phase bf16 MFMA GEMM (m201 template; hoisted addressing) ----------
#define BK 64
#define NT (IN_F / BK)   // 64 K-tiles

#define ASLOT(buf, ks) (((buf) * 2 + (ks)) * 8192)
#define BSLOT(buf, ks) (32768 + ((buf) * 2 + (ks)) * 8192)
#define KOFF(kt, ks)   ((kt) * BK + (ks) * 32)

#define VMCNT(n) asm volatile("s_waitcnt vmcnt(" #n ")" ::: "memory")
#define LGKM0    asm volatile("s_waitcnt lgkmcnt(0)" ::: "memory")
#define BARR()   __builtin_amdgcn_s_barrier()

__global__ __launch_bounds__(512, 2) void gemm8p(
    const u16* __restrict__ A,
    const u16* __restrict__ B,
    const float* __restrict__ bias,
    float* __restrict__ C) {
    __shared__ u16 lds[65536];   // 128 KiB

    const int tid  = threadIdx.x;
    const int lane = tid & 63;
    const int ln15 = lane & 15;
    const int l16  = lane >> 4;
    const int wv   = tid >> 6;
    const int wr   = wv >> 2;
    const int wc   = wv & 3;
    const int wrow = wr * 128;
    const int wcol = wc * 64;

    // XCD-bijective swizzle, column-major within XCD (R12: FETCH 295->197 MB)
    const int bid = blockIdx.x;
    const int xcd = bid & 7;
    const int j   = bid >> 3;            // 0..63 within XCD
    const int by  = xcd * 4 + (j & 3);   // 0..31
    const int bx  = j >> 2;              // 0..15
    const int arow = by * 256;
    const int brow = bx * 256;

    // hoisted per-thread global staging base pointers (addressing R13):
    // STAGE source = base + (kt*64 + ks*32) elements — additive only in-loop.
    const int q0 = tid,       r0 = q0 >> 2, c0 = (q0 & 3) ^ ((r0 >> 1) & 3);
    const int q1 = tid + 512, r1 = q1 >> 2, c1 = (q1 & 3) ^ ((r1 >> 1) & 3);
    const u16* pA0 = A + (size_t)(arow + r0) * IN_F + c0 * 8;
    const u16* pA1 = A + (size_t)(arow + r1) * IN_F + c1 * 8;
    const u16* pB0 = B + (size_t)(brow + r0) * IN_F + c0 * 8;
    const u16* pB1 = B + (size_t)(brow + r1) * IN_F + c1 * 8;

    f32x4 acc[8][4];
    #pragma unroll
    for (int m = 0; m < 8; m++)
        #pragma unroll
        for (int n = 0; n < 4; n++)
            acc[m][n] = {0.f, 0.f, 0.f, 0.f};

    #define STAGE2(p0, p1, koff, slot) do {                                             \
        __builtin_amdgcn_global_load_lds(                                               \
            (const __attribute__((address_space(1))) unsigned int*)((p0) + (koff)),     \
            (__attribute__((address_space(3))) unsigned int*)&lds[(slot) + tid * 8],    \
            16, 0, 0);                                                                  \
        __builtin_amdgcn_global_load_lds(                                               \
            (const __attribute__((address_space(1))) unsigned int*)((p1) + (koff)),     \
            (__attribute__((address_space(3))) unsigned int*)&lds[(slot) + (tid + 512) * 8], \
            16, 0, 0);                                                                  \
    } while (0)

    #define READ_A(mh, ks, buf) do {                                                    \
        _Pragma("unroll")                                                               \
        for (int i_ = 0; i_ < 4; i_++) {                                                \
            int row_ = wrow + ((mh) * 4 + i_) * 16 + ln15;                              \
            int cc_  = l16 ^ ((row_ >> 1) & 3);                                         \
            aF[i_] = *(const bf16x8*)&lds[ASLOT(buf, ks) + row_ * 32 + cc_ * 8];        \
        } } while (0)

    #define READ_B(ks, buf) do {                                                       \
        _Pragma("unroll")                                                               \
        for (int i_ = 0; i_ < 4; i_++) {                                                \
            int row_ = wcol + i_ * 16 + ln15;                                           \
            int cc_  = l16 ^ ((row_ >> 1) & 3);                                         \
            bF[i_] = *(const bf16x8*)&lds[BSLOT(buf, ks) + row_ * 32 + cc_ * 8];        \
        } } while (0)

    #define MFMAQ(mh) do {                                                              \
        __builtin_amdgcn_s_setprio(1);                                                  \
        _Pragma("unroll")                                                               \
        for (int i_ = 0; i_ < 4; i_++)                                                  \
            _Pragma("unroll")                                                           \
            for (int n_ = 0; n_ < 4; n_++)                                              \
                acc[(mh) * 4 + i_][n_] = __builtin_amdgcn_mfma_f32_16x16x32_bf16(       \
                    aF[i_], bF[n_], acc[(mh) * 4 + i_][n_], 0, 0, 0);                   \
        __builtin_amdgcn_s_setprio(0);                                                  \
    } while (0)

    STAGE2(pB0, pB1, KOFF(0, 0), BSLOT(0, 0));
    STAGE2(pA0, pA1, KOFF(0, 0), ASLOT(0, 0));
    STAGE2(pB0, pB1, KOFF(0, 1), BSLOT(0, 1));
    STAGE2(pA0, pA1, KOFF(0, 1), ASLOT(0, 1));
    VMCNT(4);
    STAGE2(pB0, pB1, KOFF(1, 0), BSLOT(1, 0));
    STAGE2(pA0, pA1, KOFF(1, 0), ASLOT(1, 0));
    STAGE2(pB0, pB1, KOFF(1, 1), BSLOT(1, 1));
    VMCNT(6);
    BARR();

    bf16x8 aF[4], bF[4];

    #pragma unroll 1
    for (int it = 0; it < NT / 2; it++) {
        const int t0 = 2 * it;
        const int ka = t0 + 1;
        const int kb = min(t0 + 2, NT - 1);   // clamp keeps loads in-bounds
        const int kc = min(t0 + 3, NT - 1);

        // ---- tile t0 (buf 0) ----
        READ_A(0, 0, 0); READ_B(0, 0);
        STAGE2(pA0, pA1, KOFF(ka, 1), ASLOT(1, 1));
        BARR(); LGKM0; MFMAQ(0); BARR();
        READ_A(1, 0, 0);
        STAGE2(pB0, pB1, KOFF(kb, 0), BSLOT(0, 0));
        BARR(); LGKM0; MFMAQ(1); BARR();
        READ_A(0, 1, 0); READ_B(1, 0);
        STAGE2(pA0, pA1, KOFF(kb, 0), ASLOT(0, 0));
        BARR(); LGKM0; MFMAQ(0); BARR();
        READ_A(1, 1, 0);
        STAGE2(pB0, pB1, KOFF(kb, 1), BSLOT(0, 1));
        VMCNT(6);
        BARR(); LGKM0; MFMAQ(1); BARR();

        // ---- tile t0+1 (buf 1) ----
        READ_A(0, 0, 1); READ_B(0, 1);
        STAGE2(pA0, pA1, KOFF(kb, 1), ASLOT(0, 1));
        BARR(); LGKM0; MFMAQ(0); BARR();
        READ_A(1, 0, 1);
        STAGE2(pB0, pB1, KOFF(kc, 0), BSLOT(1, 0));
        BARR(); LGKM0; MFMAQ(1); BARR();
        READ_A(0, 1, 1); READ_B(1, 1);
        STAGE2(pA0, pA1, KOFF(kc, 0), ASLOT(1, 0));
        BARR(); LGKM0; MFMAQ(0); BARR();
        READ_A(1, 1, 1);
        STAGE2(pB0, pB1, KOFF(kc, 1), BSLOT(1, 1));
        VMCNT(6);
        BARR(); LGKM0; MFMAQ(1); BARR();
    }
    VMCNT(0);

    // epilogue: nt stores — C is never re-read; keep L2/L3 for A/B panels
    const int cr = l16 * 4;
    #pragma unroll
    for (int n = 0; n < 4; n++) {
        int col = brow + wcol + n * 16 + ln15;
        float bv = bias[col];
        #pragma unroll
        for (int m = 0; m < 8; m++) {
            int rr0 = arow + wrow + m * 16 + cr;
            #pragma unroll
            for (int j2 = 0; j2 < 4; j2++) {
                float vv = acc[m][n][j2] + bv;
                __builtin_nontemporal_store(vv, &C[(size_t)(rr0 + j2) * OUT_F + col]);
            }
        }
    }
}

// ---------- launch ----------
extern "C" void kernel_launch(void* const* d_in, const int* in_sizes, int n_in,
                              void* d_out, int out_size, void* d_ws, size_t ws_size,
                              hipStream_t stream) {
    const float* x    = (const float*)d_in[0];
    const float* w    = (const float*)d_in[1];
    const float* bias = (const float*)d_in[2];
    float* out = (float*)d_out;

    char* ws = (char*)d_ws;
    u32* scal  = (u32*)(ws + 0);                             // 16 u32
    u16* w16   = (u16*)(ws + 65536);                         // 33.5 MB
    u16* x16   = (u16*)(ws + 65536 + (size_t)NW * 2);        // 67 MB
    // cand/cpos live in d_out (134 MB): read only by mid/finalize,
    // fully overwritten by gemm8p afterwards.  8 MB total.
    u32* cand  = (u32*)out;                                  // 4 MB
    u32* cpos  = cand + CAND_CAP;                            // 4 MB

    hipMemsetAsync(scal, 0, 64, stream);

    scanw_kernel<<<1024, 256, 0, stream>>>((const uint4*)w, w16, cand, cpos, scal);
    mid_kernel<<<2049, 1024, 0, stream>>>(cand, (const uint4*)w, (const f32x4*)x,
                                          x16, scal);
    finalize_w_kernel<<<2048, 256, 0, stream>>>(cand, cpos, (const u32x4*)w,
                                                w16, scal);

    gemm8p<<<512, 512, 0, stream>>>(x16, w16, bias, out);
}

// Round 14
// 326.731 us; speedup vs baseline: 1.0335x; 1.0206x over previous
//
#include <hip/hip_runtime.h>

#define IN_F   4096
#define OUT_F  4096
#define N_TOK  8192
#define NW     (OUT_F * IN_F)          // 16777216 weight elements
#define SEL_TARGET 8388608u            // 0-based ascending index of kth (= NW - MAX_ITER)
#define CAND_CAP (1u << 20)            // 1M keys (expected ~205K)

// Magnitude window (f32 bit patterns, sign stripped): kth is the median of
// |w| ~ U[0, 2^-6)  =>  ~2^-7 = 0x3C000000 with sigma ~1.9e-6.  Window ~±50 sigma.
#define LO_BITS 0x3BFCA000u            // 0.0077133
#define HI_BITS 0x3C018000u            // 0.0079041

typedef unsigned int  u32;
typedef unsigned short u16;

typedef __bf16 bf16x8 __attribute__((ext_vector_type(8)));
typedef float  f32x4  __attribute__((ext_vector_type(4)));
typedef u32    u32x4  __attribute__((ext_vector_type(4)));   // nt-load capable

// scal layout: [2]=kth bits  [3]=win cand count  [4]=count below LO
//              [6]=overflow flag  [7]=fallback gate
// ---------- helpers ----------
__device__ inline u16 f2bf_rne(float f) {
    u32 u = __float_as_uint(f);
    u32 r = (u + 0x7fffu + ((u >> 16) & 1u)) >> 16;
    return (u16)r;
}

// ---------- K1: w-scan — provisional w16 write, count<LO, window compact ----------
__global__ __launch_bounds__(256) void scanw_kernel(
    const uint4* __restrict__ wb, u16* __restrict__ w16,
    u32* __restrict__ cand, u32* __restrict__ cpos,
    u32* __restrict__ scal) {
    __shared__ u32 lbuf[4096];
    __shared__ u32 lpos[4096];
    __shared__ u32 lcnt, gbase, lblw;
    if (threadIdx.x == 0) { lcnt = 0; lblw = 0; }
    __syncthreads();

    const int base = blockIdx.x * 4096;   // uint4 units; 1024 blocks * 4096 = NW/4
    u32 cntb = 0;
    #pragma unroll 4
    for (int j = 0; j < 16; j++) {
        const int vi = base + threadIdx.x + j * 256;
        uint4 v = wb[vi];
        u32 r[4] = {v.x, v.y, v.z, v.w};
        ushort4 o;
        u16* op = (u16*)&o;
        #pragma unroll
        for (int e = 0; e < 4; e++) {
            u32 kk = r[e] & 0x7fffffffu;
            cntb += (kk < LO_BITS) ? 1u : 0u;
            // provisional mask at LO: exact for all entries outside the window
            op[e] = (kk >= LO_BITS) ? f2bf_rne(__uint_as_float(r[e])) : (u16)0;
            if (kk >= LO_BITS && kk < HI_BITS) {
                u32 idx = atomicAdd(&lcnt, 1u);
                if (idx < 4096) { lbuf[idx] = kk; lpos[idx] = (u32)vi * 4u + e; }
                else scal[6] = 1u;                 // per-block overflow -> fallback
            }
        }
        *(ushort4*)&w16[(size_t)vi * 4] = o;
    }
    #pragma unroll
    for (int off = 32; off; off >>= 1) cntb += __shfl_down(cntb, off);
    if ((threadIdx.x & 63) == 0) atomicAdd(&lblw, cntb);
    __syncthreads();
    if (threadIdx.x == 0) {
        gbase = atomicAdd(&scal[3], min(lcnt, 4096u));
        atomicAdd(&scal[4], lblw);
    }
    __syncthreads();
    const u32 n = min(lcnt, 4096u), gb = gbase;
    for (u32 i = threadIdx.x; i < n; i += 256)
        if (gb + i < CAND_CAP) { cand[gb + i] = lbuf[i]; cpos[gb + i] = lpos[i]; }
}

// ---------- K2: block 0 = exact kth among window candidates; blocks 1..2048 = x->bf16 ----------
#define SCAN1024(part, t)                                            \
    do { _Pragma("unroll")                                           \
        for (int off_ = 1; off_ < 1024; off_ <<= 1) {                \
            u32 v_ = ((t) >= off_) ? part[(t) - off_] : 0u;          \
            __syncthreads();                                         \
            part[t] += v_;                                           \
            __syncthreads();                                         \
        } } while (0)

__global__ __launch_bounds__(1024) void mid_kernel(const u32* __restrict__ cand,
                                                   const uint4* __restrict__ wb,
                                                   const f32x4* __restrict__ xb,
                                                   u16* __restrict__ x16,
                                                   u32* __restrict__ scal) {
    if (blockIdx.x != 0) {
        const int stride = 2048 * 1024;
        for (int i = (blockIdx.x - 1) * 1024 + threadIdx.x;
             i < (N_TOK * IN_F) / 4; i += stride) {
            f32x4 v = __builtin_nontemporal_load(&xb[i]);   // read-once stream
            ushort4 o;
            o.x = f2bf_rne(v.x);
            o.y = f2bf_rne(v.y);
            o.z = f2bf_rne(v.z);
            o.w = f2bf_rne(v.w);
            *(ushort4*)&x16[(size_t)i * 4] = o;
        }
        return;
    }

    __shared__ u32 h[2048];
    __shared__ u32 part[1024];
    __shared__ u32 sh[2];
    const int t = threadIdx.x;
    const u32 n = scal[3], below = scal[4], ovf = scal[6];
    const bool valid = (n > 0) && (n <= CAND_CAP) && (ovf == 0) &&
                       (below <= SEL_TARGET) && (SEL_TARGET < below + n);

    if (valid) {
        u32 tgt = SEL_TARGET - below;
        const uint4* c4 = (const uint4*)cand;
        const u32 n4 = n >> 2;

        // L1: 624 bins over (key - LO) >> 9  (contention-free: <=512/bin)
        h[t] = 0; h[t + 1024] = 0;
        __syncthreads();
        for (u32 i = t; i < n4; i += 1024) {
            uint4 v = c4[i];
            atomicAdd(&h[(v.x - LO_BITS) >> 9], 1u);
            atomicAdd(&h[(v.y - LO_BITS) >> 9], 1u);
            atomicAdd(&h[(v.z - LO_BITS) >> 9], 1u);
            atomicAdd(&h[(v.w - LO_BITS) >> 9], 1u);
        }
        for (u32 i = (n4 << 2) + t; i < n; i += 1024)
            atomicAdd(&h[(cand[i] - LO_BITS) >> 9], 1u);
        __syncthreads();
        u32 c = h[t];
        part[t] = c;
        __syncthreads();
        SCAN1024(part, t);
        u32 cum = (t == 0) ? 0u : part[t - 1];
        if (tgt >= cum && tgt < cum + c) { sh[0] = (u32)t; sh[1] = tgt - cum; }
        __syncthreads();
        const u32 b1 = sh[0];
        tgt = sh[1];
        __syncthreads();

        // L2: exact — 512 bins over (key - LO) & 511, filtered to b1
        h[t] = 0; h[t + 1024] = 0;
        __syncthreads();
        for (u32 i = t; i < n4; i += 1024) {
            uint4 v = c4[i];
            u32 d0 = v.x - LO_BITS, d1 = v.y - LO_BITS,
                d2 = v.z - LO_BITS, d3 = v.w - LO_BITS;
            if ((d0 >> 9) == b1) atomicAdd(&h[d0 & 511u], 1u);
            if ((d1 >> 9) == b1) atomicAdd(&h[d1 & 511u], 1u);
            if ((d2 >> 9) == b1) atomicAdd(&h[d2 & 511u], 1u);
            if ((d3 >> 9) == b1) atomicAdd(&h[d3 & 511u], 1u);
        }
        for (u32 i = (n4 << 2) + t; i < n; i += 1024) {
            u32 d = cand[i] - LO_BITS;
            if ((d >> 9) == b1) atomicAdd(&h[d & 511u], 1u);
        }
        __syncthreads();
        c = (t < 512) ? h[t] : 0u;
        part[t] = c;
        __syncthreads();
        SCAN1024(part, t);
        cum = (t == 0) ? 0u : part[t - 1];
        if (tgt >= cum && tgt < cum + c)
            scal[2] = LO_BITS + (b1 << 9) + (u32)t;   // kth |w| bit pattern
        return;
    }

    // ---- embedded exact fallback (single block, 3-level radix over all keys).
    // Never taken for the expected distribution; correct (slow) otherwise.
    if (t == 0) scal[7] = 1u;    // finalize_w must do a full rewrite
    u32 tgt = SEL_TARGET;
    const int nvec = NW / 4;
    h[t] = 0; h[t + 1024] = 0;
    __syncthreads();
    for (int i = t; i < nvec; i += 1024) {
        uint4 v = wb[i];
        atomicAdd(&h[(v.x & 0x7fffffffu) >> 20], 1u);
        atomicAdd(&h[(v.y & 0x7fffffffu) >> 20], 1u);
        atomicAdd(&h[(v.z & 0x7fffffffu) >> 20], 1u);
        atomicAdd(&h[(v.w & 0x7fffffffu) >> 20], 1u);
    }
    __syncthreads();
    u32 a0 = h[2 * t], a1 = h[2 * t + 1];
    part[t] = a0 + a1;
    __syncthreads();
    SCAN1024(part, t);
    u32 cum = (t == 0) ? 0u : part[t - 1];
    if (tgt >= cum && tgt < cum + a0) { sh[0] = (u32)(2 * t);     sh[1] = tgt - cum; }
    cum += a0;
    if (tgt >= cum && tgt < cum + a1) { sh[0] = (u32)(2 * t + 1); sh[1] = tgt - cum; }
    __syncthreads();
    const u32 b1f = sh[0];
    tgt = sh[1];
    __syncthreads();

    h[t] = 0; h[t + 1024] = 0;
    __syncthreads();
    for (int i = t; i < nvec; i += 1024) {
        uint4 v = wb[i];
        u32 k[4] = {v.x & 0x7fffffffu, v.y & 0x7fffffffu,
                    v.z & 0x7fffffffu, v.w & 0x7fffffffu};
        #pragma unroll
        for (int e = 0; e < 4; e++)
            if ((k[e] >> 20) == b1f) atomicAdd(&h[(k[e] >> 9) & 2047u], 1u);
    }
    __syncthreads();
    a0 = h[2 * t]; a1 = h[2 * t + 1];
    part[t] = a0 + a1;
    __syncthreads();
    SCAN1024(part, t);
    cum = (t == 0) ? 0u : part[t - 1];
    if (tgt >= cum && tgt < cum + a0) { sh[0] = (u32)(2 * t);     sh[1] = tgt - cum; }
    cum += a0;
    if (tgt >= cum && tgt < cum + a1) { sh[0] = (u32)(2 * t + 1); sh[1] = tgt - cum; }
    __syncthreads();
    const u32 pfx22 = (b1f << 11) | sh[0];
    tgt = sh[1];
    __syncthreads();

    h[t] = 0; h[t + 1024] = 0;
    __syncthreads();
    for (int i = t; i < nvec; i += 1024) {
        uint4 v = wb[i];
        u32 k[4] = {v.x & 0x7fffffffu, v.y & 0x7fffffffu,
                    v.z & 0x7fffffffu, v.w & 0x7fffffffu};
        #pragma unroll
        for (int e = 0; e < 4; e++)
            if ((k[e] >> 9) == pfx22) atomicAdd(&h[k[e] & 511u], 1u);
    }
    __syncthreads();
    u32 c = (t < 512) ? h[t] : 0u;
    part[t] = c;
    __syncthreads();
    SCAN1024(part, t);
    cum = (t == 0) ? 0u : part[t - 1];
    if (tgt >= cum && tgt < cum + c)
        scal[2] = (pfx22 << 9) | (u32)t;
}

// ---------- K3: finalize w16 ----------
__global__ __launch_bounds__(256) void finalize_w_kernel(
    const u32* __restrict__ cand, const u32* __restrict__ cpos,
    const u32x4* __restrict__ wb, u16* __restrict__ w16,
    const u32* __restrict__ scal) {
    const u32 kth = scal[2];
    const u32 stride = gridDim.x * blockDim.x;
    if (scal[7] == 1u) {
        const u32 nvec = NW / 4;
        for (u32 i = blockIdx.x * blockDim.x + threadIdx.x; i < nvec; i += stride) {
            u32x4 v = __builtin_nontemporal_load(&wb[i]);
            ushort4 o;
            o.x = ((v.x & 0x7fffffffu) >= kth) ? f2bf_rne(__uint_as_float(v.x)) : (u16)0;
            o.y = ((v.y & 0x7fffffffu) >= kth) ? f2bf_rne(__uint_as_float(v.y)) : (u16)0;
            o.z = ((v.z & 0x7fffffffu) >= kth) ? f2bf_rne(__uint_as_float(v.z)) : (u16)0;
            o.w = ((v.w & 0x7fffffffu) >= kth) ? f2bf_rne(__uint_as_float(v.w)) : (u16)0;
            *(ushort4*)&w16[(size_t)i * 4] = o;
        }
    } else {
        const u32 n = min(scal[3], CAND_CAP);
        for (u32 i = blockIdx.x * blockDim.x + threadIdx.x; i < n; i += stride)
            if (cand[i] < kth) w16[cpos[i]] = (u16)0;
    }
}

// ---------- K4: 256x256 8-phase bf16 MFMA GEMM — persistent 2-tile blocks ----------
#define BK 64
#define NT (IN_F / BK)   // 64 K-tiles

#define ASLOT(buf, ks) (((buf) * 2 + (ks)) * 8192)
#define BSLOT(buf, ks) (32768 + ((buf) * 2 + (ks)) * 8192)
#define KOFF(kt, ks)   ((kt) * BK + (ks) * 32)

#define VMCNT(n) asm volatile("s_waitcnt vmcnt(" #n ")" ::: "memory")
#define LGKM0    asm volatile("s_waitcnt lgkmcnt(0)" ::: "memory")
#define BARR()   __builtin_amdgcn_s_barrier()

__global__ __launch_bounds__(512, 2) void gemm8p(
    const u16* __restrict__ A,
    const u16* __restrict__ B,
    const float* __restrict__ bias,
    float* __restrict__ C) {
    __shared__ u16 lds[65536];   // 128 KiB

    const int tid  = threadIdx.x;
    const int lane = tid & 63;
    const int ln15 = lane & 15;
    const int l16  = lane >> 4;
    const int wv   = tid >> 6;
    const int wr   = wv >> 2;
    const int wc   = wv & 3;
    const int wrow = wr * 128;
    const int wcol = wc * 64;

    // 256 persistent blocks (1/CU, single round); each does TWO M-tiles at one bx
    // (B-panel reuse).  XCD-bijective: xcd owns by in [xcd*4, xcd*4+4).
    const int bid = blockIdx.x;
    const int xcd = bid & 7;
    const int j   = bid >> 3;            // 0..31
    const int bx  = j >> 1;              // 0..15
    const int mm  = j & 1;
    const int by0 = xcd * 4 + mm * 2;    // tiles by0, by0+1
    const int brow = bx * 256;
    const int arow0 = by0 * 256;

    // hoisted per-thread global staging base pointers; additive K-offsets in-loop
    const int q0 = tid,       r0 = q0 >> 2, c0 = (q0 & 3) ^ ((r0 >> 1) & 3);
    const int q1 = tid + 512, r1 = q1 >> 2, c1 = (q1 & 3) ^ ((r1 >> 1) & 3);
    const u16* pA0 = A + (size_t)(arow0 + r0) * IN_F + c0 * 8;
    const u16* pA1 = A + (size_t)(arow0 + r1) * IN_F + c1 * 8;
    const u16* pB0 = B + (size_t)(brow + r0) * IN_F + c0 * 8;
    const u16* pB1 = B + (size_t)(brow + r1) * IN_F + c1 * 8;

    f32x4 acc[8][4];
    #pragma unroll
    for (int m = 0; m < 8; m++)
        #pragma unroll
        for (int n = 0; n < 4; n++)
            acc[m][n] = {0.f, 0.f, 0.f, 0.f};

    #define STAGE2(p0, p1, koff, slot) do {                                             \
        __builtin_amdgcn_global_load_lds(                                               \
            (const __attribute__((address_space(1))) unsigned int*)((p0) + (koff)),     \
            (__attribute__((address_space(3))) unsigned int*)&lds[(slot) + tid * 8],    \
            16, 0, 0);                                                                  \
        __builtin_amdgcn_global_load_lds(                                               \
            (const __attribute__((address_space(1))) unsigned int*)((p1) + (koff)),     \
            (__attribute__((address_space(3))) unsigned int*)&lds[(slot) + (tid + 512) * 8], \
            16, 0, 0);                                                                  \
    } while (0)

    #define READ_A(mh, ks, buf) do {                                                    \
        _Pragma("unroll")                                                               \
        for (int i_ = 0; i_ < 4; i_++) {                                                \
            int row_ = wrow + ((mh) * 4 + i_) * 16 + ln15;                              \
            int cc_  = l16 ^ ((row_ >> 1) & 3);                                         \
            aF[i_] = *(const bf16x8*)&lds[ASLOT(buf, ks) + row_ * 32 + cc_ * 8];        \
        } } while (0)

    #define READ_B(ks, buf) do {                                                       \
        _Pragma("unroll")                                                               \
        for (int i_ = 0; i_ < 4; i_++) {                                                \
            int row_ = wcol + i_ * 16 + ln15;                                           \
            int cc_  = l16 ^ ((row_ >> 1) & 3);                                         \
            bF[i_] = *(const bf16x8*)&lds[BSLOT(buf, ks) + row_ * 32 + cc_ * 8];        \
        } } while (0)

    #define MFMAQ(mh) do {                                                              \
        __builtin_amdgcn_s_setprio(1);                                                  \
        _Pragma("unroll")                                                               \
        for (int i_ = 0; i_ < 4; i_++)                                                  \
            _Pragma("unroll")                                                           \
            for (int n_ = 0; n_ < 4; n_++)                                              \
                acc[(mh) * 4 + i_][n_] = __builtin_amdgcn_mfma_f32_16x16x32_bf16(       \
                    aF[i_], bF[n_], acc[(mh) * 4 + i_][n_], 0, 0, 0);                   \
        __builtin_amdgcn_s_setprio(0);                                                  \
    } while (0)

    #define PROLOG7() do {                                                              \
        STAGE2(pB0, pB1, KOFF(0, 0), BSLOT(0, 0));                                      \
        STAGE2(pA0, pA1, KOFF(0, 0), ASLOT(0, 0));                                      \
        STAGE2(pB0, pB1, KOFF(0, 1), BSLOT(0, 1));                                      \
        STAGE2(pA0, pA1, KOFF(0, 1), ASLOT(0, 1));                                      \
        STAGE2(pB0, pB1, KOFF(1, 0), BSLOT(1, 0));                                      \
        STAGE2(pA0, pA1, KOFF(1, 0), ASLOT(1, 0));                                      \
        STAGE2(pB0, pB1, KOFF(1, 1), BSLOT(1, 1));                                      \
    } while (0)

    PROLOG7();
    VMCNT(6);
    BARR();

    bf16x8 aF[4], bF[4];

    #pragma unroll 1
    for (int tile = 0; tile < 2; ++tile) {
        #pragma unroll 1
        for (int it = 0; it < NT / 2; it++) {
            const int t0 = 2 * it;
            const int ka = t0 + 1;
            const int kb = min(t0 + 2, NT - 1);   // clamp keeps loads in-bounds
            const int kc = min(t0 + 3, NT - 1);

            // ---- K-tile t0 (buf 0) ----
            READ_A(0, 0, 0); READ_B(0, 0);
            STAGE2(pA0, pA1, KOFF(ka, 1), ASLOT(1, 1));
            BARR(); LGKM0; MFMAQ(0); BARR();
            READ_A(1, 0, 0);
            STAGE2(pB0, pB1, KOFF(kb, 0), BSLOT(0, 0));
            BARR(); LGKM0; MFMAQ(1); BARR();
            READ_A(0, 1, 0); READ_B(1, 0);
            STAGE2(pA0, pA1, KOFF(kb, 0), ASLOT(0, 0));
            BARR(); LGKM0; MFMAQ(0); BARR();
            READ_A(1, 1, 0);
            STAGE2(pB0, pB1, KOFF(kb, 1), BSLOT(0, 1));
            VMCNT(6);
            BARR(); LGKM0; MFMAQ(1); BARR();

            // ---- K-tile t0+1 (buf 1) ----
            READ_A(0, 0, 1); READ_B(0, 1);
            STAGE2(pA0, pA1, KOFF(kb, 1), ASLOT(0, 1));
            BARR(); LGKM0; MFMAQ(0); BARR();
            READ_A(1, 0, 1);
            STAGE2(pB0, pB1, KOFF(kc, 0), BSLOT(1, 0));
            BARR(); LGKM0; MFMAQ(1); BARR();
            READ_A(0, 1, 1); READ_B(1, 1);
            STAGE2(pA0, pA1, KOFF(kc, 0), ASLOT(1, 0));
            BARR(); LGKM0; MFMAQ(0); BARR();
            READ_A(1, 1, 1);
            STAGE2(pB0, pB1, KOFF(kc, 1), BSLOT(1, 1));
            VMCNT(6);
            BARR(); LGKM0; MFMAQ(1); BARR();
        }
        VMCNT(0);    // drain trailing prefetches (LDS dests are per-thread-exclusive)

        if (tile == 0) {
            // advance A pointers to the next M-tile and pre-stage its prologue;
            // the stages fly while we run tile-0's epilogue below.
            pA0 += (size_t)256 * IN_F;
            pA1 += (size_t)256 * IN_F;
            PROLOG7();
        }

        // epilogue for this tile: nt stores (C never re-read)
        const int arowt = arow0 + tile * 256;
        const int cr = l16 * 4;
        #pragma unroll
        for (int n = 0; n < 4; n++) {
            int col = brow + wcol + n * 16 + ln15;
            float bv = bias[col];
            #pragma unroll
            for (int m = 0; m < 8; m++) {
                int rr0 = arowt + wrow + m * 16 + cr;
                #pragma unroll
                for (int j2 = 0; j2 < 4; j2++) {
                    float vv = acc[m][n][j2] + bv;
                    __builtin_nontemporal_store(vv, &C[(size_t)(rr0 + j2) * OUT_F + col]);
                }
            }
        }

        if (tile == 0) {
            #pragma unroll
            for (int m = 0; m < 8; m++)
                #pragma unroll
                for (int n = 0; n < 4; n++)
                    acc[m][n] = {0.f, 0.f, 0.f, 0.f};
            VMCNT(6);    // first 4 half-tiles of next M-tile landed; 6 in flight
            BARR();
        }
    }
}

// ---------- launch ----------
extern "C" void kernel_launch(void* const* d_in, const int* in_sizes, int n_in,
                              void* d_out, int out_size, void* d_ws, size_t ws_size,
                              hipStream_t stream) {
    const float* x    = (const float*)d_in[0];
    const float* w    = (const float*)d_in[1];
    const float* bias = (const float*)d_in[2];
    float* out = (float*)d_out;

    char* ws = (char*)d_ws;
    u32* scal  = (u32*)(ws + 0);                             // 16 u32
    u16* w16   = (u16*)(ws + 65536);                         // 33.5 MB
    u16* x16   = (u16*)(ws + 65536 + (size_t)NW * 2);        // 67 MB
    // cand/cpos live in d_out (134 MB): read only by mid/finalize,
    // fully overwritten by gemm8p afterwards.  8 MB total.
    u32* cand  = (u32*)out;                                  // 4 MB
    u32* cpos  = cand + CAND_CAP;                            // 4 MB

    hipMemsetAsync(scal, 0, 64, stream);

    scanw_kernel<<<1024, 256, 0, stream>>>((const uint4*)w, w16, cand, cpos, scal);
    mid_kernel<<<2049, 1024, 0, stream>>>(cand, (const uint4*)w, (const f32x4*)x,
                                          x16, scal);
    finalize_w_kernel<<<2048, 256, 0, stream>>>(cand, cpos, (const u32x4*)w,
                                                w16, scal);

    gemm8p<<<256, 512, 0, stream>>>(x16, w16, bias, out);
}